// Round 4
// baseline (655.838 us; speedup 1.0000x reference)
//
#include <hip/hip_runtime.h>
#include <cstdint>
#include <cstddef>

#define N_NODES 100000
#define N_EDGES 1600000

// ---- bucketed counting-sort CSR parameters ----
constexpr int NPB = 512;                               // nodes per bucket (2^9)
constexpr int NBUCK = (N_NODES + NPB - 1) / NPB;       // 196
constexpr int EPB = 8192;                              // edges per block in B1/B2
constexpr int NCHUNK = (N_EDGES + EPB - 1) / EPB;      // 196

typedef _Float16 half8 __attribute__((ext_vector_type(8)));
typedef _Float16 half2v __attribute__((ext_vector_type(2)));
typedef float f32x4 __attribute__((ext_vector_type(4)));

// ================================================================= CSR build
__global__ __launch_bounds__(256) void b1_hist(const int* __restrict__ dst,
                                               int* __restrict__ bbc) {
    __shared__ int hist[NBUCK];
    int t = threadIdx.x;
    if (t < NBUCK) hist[t] = 0;
    __syncthreads();
    int base = blockIdx.x * EPB;
#pragma unroll
    for (int i = 0; i < EPB / 256; ++i) {
        int e = base + i * 256 + t;
        if (e < N_EDGES) atomicAdd(&hist[dst[e] >> 9], 1);
    }
    __syncthreads();
    if (t < NBUCK) bbc[t * NCHUNK + blockIdx.x] = hist[t];
}

__global__ void b_scan(int* __restrict__ bbc, int* __restrict__ bucketOff,
                       int* __restrict__ rowStart) {
    __shared__ int tot[NBUCK];
    int t = threadIdx.x;
    if (t < NBUCK) {
        int run = 0;
        for (int blk = 0; blk < NCHUNK; ++blk) {
            int idx = t * NCHUNK + blk;
            int c = bbc[idx];
            bbc[idx] = run;
            run += c;
        }
        tot[t] = run;
    }
    __syncthreads();
    if (t == 0) {
        int acc = 0;
        for (int b = 0; b < NBUCK; ++b) {
            bucketOff[b] = acc;
            acc += tot[b];
        }
        bucketOff[NBUCK] = acc;
        rowStart[N_NODES] = acc;
    }
}

__global__ __launch_bounds__(256) void b2_scatter(const int* __restrict__ src,
                                                  const int* __restrict__ dst,
                                                  const int* __restrict__ bbc,
                                                  const int* __restrict__ bucketOff,
                                                  int* __restrict__ staged) {
    __shared__ int cnt[NBUCK];
    __shared__ int base[NBUCK];
    int t = threadIdx.x;
    if (t < NBUCK) {
        cnt[t] = 0;
        base[t] = bucketOff[t] + bbc[t * NCHUNK + blockIdx.x];
    }
    __syncthreads();
    int ebase = blockIdx.x * EPB;
#pragma unroll
    for (int i = 0; i < EPB / 256; ++i) {
        int e = ebase + i * 256 + t;
        if (e < N_EDGES) {
            int d = dst[e];
            int b = d >> 9;
            int r = atomicAdd(&cnt[b], 1);
            staged[base[b] + r] = ((d & 511) << 17) | src[e];
        }
    }
}

__global__ __launch_bounds__(256) void b3_sort(const int* __restrict__ staged,
                                               const int* __restrict__ bucketOff,
                                               int* __restrict__ rowStart,
                                               float* __restrict__ normv,
                                               int* __restrict__ colIdx) {
    __shared__ int hist[NPB];
    __shared__ int sc0[NPB], sc1[NPB];
    __shared__ int cursor[NPB];
    int t = threadIdx.x;
    int b = blockIdx.x;
    int e0 = bucketOff[b], e1 = bucketOff[b + 1];
    int ne = e1 - e0;
    int node0 = b * NPB;
    int nn = min(NPB, N_NODES - node0);

    for (int j = t; j < NPB; j += 256) hist[j] = 0;
    __syncthreads();
    for (int idx = t; idx < ne; idx += 256)
        atomicAdd(&hist[staged[e0 + idx] >> 17], 1);
    __syncthreads();
    for (int j = t; j < NPB; j += 256) sc0[j] = hist[j];
    __syncthreads();
    int* s = sc0;
    int* d = sc1;
    for (int off = 1; off < NPB; off <<= 1) {
        for (int j = t; j < NPB; j += 256) d[j] = s[j] + (j >= off ? s[j - off] : 0);
        __syncthreads();
        int* tmp = s; s = d; d = tmp;
    }
    for (int j = t; j < NPB; j += 256) {
        int excl = s[j] - hist[j];
        cursor[j] = excl;
        if (j < nn) {
            rowStart[node0 + j] = e0 + excl;
            normv[node0 + j] = (float)(1.0 / sqrt((double)(hist[j] + 1)));
        }
    }
    __syncthreads();
    for (int idx = t; idx < ne; idx += 256) {
        int v = staged[e0 + idx];
        int dl = v >> 17;
        int sn = v & 0x1FFFF;
        int r = atomicAdd(&cursor[dl], 1);
        colIdx[e0 + r] = sn;
    }
}

// ================================================== weight prep (tiny)
__global__ void wc_kernel(const float* __restrict__ Wp, const float* __restrict__ bp,
                          const float* __restrict__ W1, float* __restrict__ Wc,
                          float* __restrict__ bc) {
    int r = blockIdx.x;
    int cc = threadIdx.x;
    float acc = 0.f;
    if (r < 256) {
        for (int k = 0; k < 128; ++k) acc = fmaf(Wp[r * 128 + k], W1[k * 128 + cc], acc);
        Wc[r * 128 + cc] = acc;
    } else {
        for (int k = 0; k < 128; ++k) acc = fmaf(bp[k], W1[k * 128 + cc], acc);
        bc[cc] = acc;
    }
}

// transpose + f16 hi/lo split: W[K][128] -> Oh/Ol[128][K]
__global__ void tsplit_kernel(const float* __restrict__ W, _Float16* __restrict__ Oh,
                              _Float16* __restrict__ Ol, int K) {
    int id = blockIdx.x * 256 + threadIdx.x;
    if (id >= K * 128) return;
    int n = id / K;
    int k = id - n * K;
    float v = W[k * 128 + n];
    _Float16 h = (_Float16)v;
    Oh[id] = h;
    Ol[id] = (_Float16)(v - (float)h);
}

// ================================ persistent-B barrier-free split-f16 GEMM
// C[r][c] = (sum_k A[r][k]*B[k][c] + bias[c]) * scale[r], stored fp16.
// Whole B (hi+lo) staged in LDS ONCE, XOR-swizzled on 16B granules: granule j
// of row n lives at group (j>>3), slot (j&7)^(n&7). After the single init
// barrier there are NO barriers: each of the 8 waves independently
// grid-strides over 16-row strips of A with depth-2 register prefetch of
// 32-k slabs.
// Register budget (round 2/3 post-mortem): the backend ignored both
// launch_bounds(512,2) and (512,1) min-waves hints, capped at 128 VGPR and
// spilled ~150-240 MB of scratch per dispatch (WRITE_SIZE 177-265 MB vs
// 25.6 ideal). Fix is structural: 16-row tile -> acc 32 + pf 16 + ah/al 8
// + misc ~25 ≈ 80 regs, fits under ANY cap >= 128. amdgpu_waves_per_eu(1,2)
// additionally clamps the scheduler's occupancy target (8-wave block,
// 1 block/CU by LDS = 2 waves/EU).
template <bool AF16, int K>
__global__ __attribute__((amdgpu_waves_per_eu(1, 2)))
__launch_bounds__(512) void mfma_gemm_p(
    const float* __restrict__ Af, const _Float16* __restrict__ Ah,
    const _Float16* __restrict__ Bth, const _Float16* __restrict__ Btl,
    const float* __restrict__ bias, const float* __restrict__ scale,
    _Float16* __restrict__ Ch, int M, int nstrip) {
    constexpr int NSLAB = K / 32;
    constexpr int JROW = K / 8;          // 16B granules per B row
    __shared__ _Float16 sBh[128 * K];
    __shared__ _Float16 sBl[128 * K];

    const int t = threadIdx.x;
    // ---- stage all of B hi+lo, swizzled (write side of the involution)
    for (int idx = t; idx < 128 * JROW; idx += 512) {
        int n = idx / JROW;
        int j = idx - n * JROW;
        int d = n * K + (((j & 7) ^ (n & 7)) << 3) + ((j >> 3) << 6);
        *(half8*)&sBh[d] = *(const half8*)(Bth + n * K + (j << 3));
        *(half8*)&sBl[d] = *(const half8*)(Btl + n * K + (j << 3));
    }
    __syncthreads();

    const int lane = t & 63;
    const int q = lane >> 4;             // k-quad: k = q*8+jj within slab
    const int mr = lane & 15;            // row/col within 16x16 tile
    const int mre = mr & 7;
    const int gw = (blockIdx.x << 3) + (t >> 6);
    const int wstride = gridDim.x << 3;

    for (int strip = gw; strip < nstrip; strip += wstride) {
        const int row0 = strip * 16;
        int ar = row0 + mr;
        if (ar >= M) ar = M - 1;

        f32x4 acc[8];
#pragma unroll
        for (int nt = 0; nt < 8; ++nt) acc[nt] = (f32x4){0.f, 0.f, 0.f, 0.f};

        f32x4 pf[2][2];                  // fp32 A prefetch, 2 slabs deep
        half8 ph[2];                     // fp16 A prefetch, 2 slabs deep

#define LOAD_SLAB(SLOT, SS)                                                    \
        {                                                                      \
            if constexpr (AF16) {                                              \
                ph[SLOT] = *(const half8*)(Ah + (size_t)ar * K + (SS) * 32 + q * 8); \
            } else {                                                           \
                const float* ap = Af + (size_t)ar * K + (SS) * 32 + q * 8;     \
                pf[SLOT][0] = *(const f32x4*)ap;                               \
                pf[SLOT][1] = *(const f32x4*)(ap + 4);                         \
            }                                                                  \
        }

        LOAD_SLAB(0, 0)
        LOAD_SLAB(1, 1)

#pragma unroll
        for (int s = 0; s < NSLAB; ++s) {
            const int sl = s & 1;
            // ---- settle/convert current A fragment (loads issued 2 slabs ago)
            half8 ah, al;
            if constexpr (AF16) {
                ah = ph[sl];
            } else {
                f32x4 a0 = pf[sl][0];
                f32x4 a1 = pf[sl][1];
#pragma unroll
                for (int jj = 0; jj < 4; ++jj) {
                    _Float16 h0 = (_Float16)a0[jj];
                    _Float16 h1 = (_Float16)a1[jj];
                    ah[jj] = h0;
                    ah[jj + 4] = h1;
                    al[jj] = (_Float16)(a0[jj] - (float)h0);
                    al[jj + 4] = (_Float16)(a1[jj] - (float)h1);
                }
            }
            // ---- issue slab s+2 loads; they fly under this slab's MFMA burst
            if (s + 2 < NSLAB) LOAD_SLAB(sl, s + 2)

            // ---- MFMA burst; B from LDS (no barrier: B is static)
            // wanted granule j = s*4 + q  ->  group s>>1, slot ((s&1)*4|q)^mre
            const int kof = ((s >> 1) << 6) + ((((s & 1) << 2) | q) ^ mre) * 8;
#pragma unroll
            for (int nt = 0; nt < 8; ++nt) {
                const int bo = (nt * 16 + mr) * K + kof;
                half8 bh = *(const half8*)&sBh[bo];
                half8 bl = *(const half8*)&sBl[bo];
                acc[nt] = __builtin_amdgcn_mfma_f32_16x16x32_f16(ah, bh, acc[nt], 0, 0, 0);
                acc[nt] = __builtin_amdgcn_mfma_f32_16x16x32_f16(ah, bl, acc[nt], 0, 0, 0);
                if constexpr (!AF16)
                    acc[nt] = __builtin_amdgcn_mfma_f32_16x16x32_f16(al, bh, acc[nt], 0, 0, 0);
            }
        }
#undef LOAD_SLAB

        // ---- epilogue: C/D layout col=mr, row=q*4+rr (bias loaded here)
#pragma unroll
        for (int rr = 0; rr < 4; ++rr) {
            int row = row0 + q * 4 + rr;
            if (row >= M) continue;
            float sc = scale[row];
#pragma unroll
            for (int nt = 0; nt < 8; ++nt) {
                float bv = bias ? bias[nt * 16 + mr] : 0.f;
                Ch[(size_t)row * 128 + nt * 16 + mr] =
                    (_Float16)((acc[nt][rr] + bv) * sc);
            }
        }
    }
}

// ------------------------------------------------------------- aggregation
// zs fp16 pre-scaled by norm[row]. out = maybe_relu(norm[i]*(sum zs[src]+zs[i])+b)
__global__ __launch_bounds__(256) void agg_kernel(const _Float16* __restrict__ zs,
                                                  const int* __restrict__ rowStart,
                                                  const int* __restrict__ colIdx,
                                                  const float* __restrict__ normv,
                                                  const float* __restrict__ bias,
                                                  float* __restrict__ outF,
                                                  _Float16* __restrict__ outH,
                                                  int doRelu) {
    int wid = (blockIdx.x * 256 + threadIdx.x) >> 6;
    int lane = threadIdx.x & 63;
    if (wid >= N_NODES) return;
    int s0 = rowStart[wid];
    int s1 = rowStart[wid + 1];
    const int c = lane * 2;
    const _Float16* zc = zs + c;

    float2 a0 = make_float2(0.f, 0.f), a1 = a0, a2 = a0, a3 = a0;
    int e = s0;
    for (; e + 8 <= s1; e += 8) {
        int i0 = colIdx[e + 0], i1 = colIdx[e + 1], i2 = colIdx[e + 2], i3 = colIdx[e + 3];
        int i4 = colIdx[e + 4], i5 = colIdx[e + 5], i6 = colIdx[e + 6], i7 = colIdx[e + 7];
        half2v v0 = *(const half2v*)(zc + (size_t)i0 * 128);
        half2v v1 = *(const half2v*)(zc + (size_t)i1 * 128);
        half2v v2 = *(const half2v*)(zc + (size_t)i2 * 128);
        half2v v3 = *(const half2v*)(zc + (size_t)i3 * 128);
        half2v v4 = *(const half2v*)(zc + (size_t)i4 * 128);
        half2v v5 = *(const half2v*)(zc + (size_t)i5 * 128);
        half2v v6 = *(const half2v*)(zc + (size_t)i6 * 128);
        half2v v7 = *(const half2v*)(zc + (size_t)i7 * 128);
        a0.x += (float)v0[0] + (float)v4[0]; a0.y += (float)v0[1] + (float)v4[1];
        a1.x += (float)v1[0] + (float)v5[0]; a1.y += (float)v1[1] + (float)v5[1];
        a2.x += (float)v2[0] + (float)v6[0]; a2.y += (float)v2[1] + (float)v6[1];
        a3.x += (float)v3[0] + (float)v7[0]; a3.y += (float)v3[1] + (float)v7[1];
    }
    if (e + 4 <= s1) {
        int i0 = colIdx[e + 0], i1 = colIdx[e + 1], i2 = colIdx[e + 2], i3 = colIdx[e + 3];
        half2v v0 = *(const half2v*)(zc + (size_t)i0 * 128);
        half2v v1 = *(const half2v*)(zc + (size_t)i1 * 128);
        half2v v2 = *(const half2v*)(zc + (size_t)i2 * 128);
        half2v v3 = *(const half2v*)(zc + (size_t)i3 * 128);
        a0.x += (float)v0[0]; a0.y += (float)v0[1];
        a1.x += (float)v1[0]; a1.y += (float)v1[1];
        a2.x += (float)v2[0]; a2.y += (float)v2[1];
        a3.x += (float)v3[0]; a3.y += (float)v3[1];
        e += 4;
    }
    for (; e < s1; ++e) {
        int i0 = colIdx[e];
        half2v v0 = *(const half2v*)(zc + (size_t)i0 * 128);
        a0.x += (float)v0[0]; a0.y += (float)v0[1];
    }

    half2v self = *(const half2v*)(zc + (size_t)wid * 128);
    float sx = (a0.x + a1.x) + (a2.x + a3.x) + (float)self[0];
    float sy = (a0.y + a1.y) + (a2.y + a3.y) + (float)self[1];
    float nd = normv[wid];
    float2 bv = *(const float2*)(bias + c);
    float ox = fmaf(nd, sx, bv.x);
    float oy = fmaf(nd, sy, bv.y);
    if (doRelu) {
        ox = fmaxf(ox, 0.f);
        oy = fmaxf(oy, 0.f);
    }
    if (outH) {
        half2v o;
        o[0] = (_Float16)ox;
        o[1] = (_Float16)oy;
        *(half2v*)(outH + (size_t)wid * 128 + c) = o;
    } else {
        *(float2*)(outF + (size_t)wid * 128 + c) = make_float2(ox, oy);
    }
}

// ---------------------------------------------------------------- launcher
extern "C" void kernel_launch(void* const* d_in, const int* in_sizes, int n_in,
                              void* d_out, int out_size, void* d_ws, size_t ws_size,
                              hipStream_t stream) {
    const float* x  = (const float*)d_in[0];
    const int* ei   = (const int*)d_in[1];
    const float* Wp = (const float*)d_in[2];
    const float* bp = (const float*)d_in[3];
    const float* W1 = (const float*)d_in[4];
    const float* b1 = (const float*)d_in[5];
    const float* W2 = (const float*)d_in[6];
    const float* b2 = (const float*)d_in[7];
    float* out = (float*)d_out;

    const int* srcIdx = ei;
    const int* dstIdx = ei + N_EDGES;

    size_t off = 0;
    auto alloc = [&](size_t bytes) -> void* {
        void* p = (char*)d_ws + off;
        off += (bytes + 511) & ~(size_t)511;
        return p;
    };
    int* rowStart   = (int*)alloc((size_t)(N_NODES + 1) * 4);
    int* colIdx     = (int*)alloc((size_t)N_EDGES * 4);
    int* staged     = (int*)alloc((size_t)N_EDGES * 4);
    int* bbc        = (int*)alloc((size_t)NBUCK * NCHUNK * 4);
    int* bucketOff  = (int*)alloc((size_t)(NBUCK + 1) * 4);
    float* normv    = (float*)alloc((size_t)N_NODES * 4);
    float* Wc       = (float*)alloc((size_t)256 * 128 * 4);
    float* bc       = (float*)alloc((size_t)128 * 4);
    _Float16* Wcth  = (_Float16*)alloc((size_t)128 * 256 * 2);
    _Float16* Wctl  = (_Float16*)alloc((size_t)128 * 256 * 2);
    _Float16* W2th  = (_Float16*)alloc((size_t)128 * 128 * 2);
    _Float16* W2tl  = (_Float16*)alloc((size_t)128 * 128 * 2);
    _Float16* zA    = (_Float16*)alloc((size_t)N_NODES * 128 * 2);
    _Float16* zB    = (_Float16*)alloc((size_t)N_NODES * 128 * 2);

    const int AB = (N_NODES + 3) / 4;           // 25000 (agg: 1 wave/node)
    constexpr int NSTRIP = (N_NODES + 15) / 16; // 6250 strips of 16 rows

    // ---- CSR build (bucketed counting sort) ----
    b1_hist<<<NCHUNK, 256, 0, stream>>>(dstIdx, bbc);
    b_scan<<<1, 256, 0, stream>>>(bbc, bucketOff, rowStart);
    b2_scatter<<<NCHUNK, 256, 0, stream>>>(srcIdx, dstIdx, bbc, bucketOff, staged);
    b3_sort<<<NBUCK, 256, 0, stream>>>(staged, bucketOff, rowStart, normv, colIdx);

    // ---- weight prep ----
    wc_kernel<<<257, 128, 0, stream>>>(Wp, bp, W1, Wc, bc);
    tsplit_kernel<<<(256 * 128 + 255) / 256, 256, 0, stream>>>(Wc, Wcth, Wctl, 256);
    tsplit_kernel<<<(128 * 128 + 255) / 256, 256, 0, stream>>>(W2, W2th, W2tl, 128);

    // ---- pipeline (all intermediates fp16, pre-scaled by norm) ----
    // zA = f16[(x @ Wc + bc) * norm]   (persistent-B, barrier-free)
    mfma_gemm_p<false, 256><<<256, 512, 0, stream>>>(x, nullptr, Wcth, Wctl, bc, normv,
                                                     zA, N_NODES, NSTRIP);
    // zB = f16[relu(norm*(sum zA[src] + zA[self]) + b1)]
    agg_kernel<<<AB, 256, 0, stream>>>(zA, rowStart, colIdx, normv, b1, nullptr, zB, 1);
    // zA (reused) = f16[(zB @ W2) * norm]   — A fp16, 2-product path
    mfma_gemm_p<true, 128><<<256, 512, 0, stream>>>(nullptr, zB, W2th, W2tl, nullptr, normv,
                                                    zA, N_NODES, NSTRIP);
    // out = fp32[norm*(sum zA[src] + zA[self]) + b2]
    agg_kernel<<<AB, 256, 0, stream>>>(zA, rowStart, colIdx, normv, b2, out, nullptr, 0);
}

// Round 5
// 460.285 us; speedup vs baseline: 1.4249x; 1.4249x over previous
//
#include <hip/hip_runtime.h>
#include <cstdint>
#include <cstddef>

#define N_NODES 100000
#define N_EDGES 1600000

// ---- bucketed counting-sort CSR parameters ----
constexpr int NPB = 512;                               // nodes per bucket (2^9)
constexpr int NBUCK = (N_NODES + NPB - 1) / NPB;       // 196
constexpr int EPB = 8192;                              // edges per block in B1/B2
constexpr int NCHUNK = (N_EDGES + EPB - 1) / EPB;      // 196

typedef _Float16 half8 __attribute__((ext_vector_type(8)));
typedef _Float16 half2v __attribute__((ext_vector_type(2)));
typedef float f32x4 __attribute__((ext_vector_type(4)));

// ================================================================= CSR build
__global__ __launch_bounds__(256) void b1_hist(const int* __restrict__ dst,
                                               int* __restrict__ bbc) {
    __shared__ int hist[NBUCK];
    int t = threadIdx.x;
    if (t < NBUCK) hist[t] = 0;
    __syncthreads();
    int base = blockIdx.x * EPB;
#pragma unroll
    for (int i = 0; i < EPB / 256; ++i) {
        int e = base + i * 256 + t;
        if (e < N_EDGES) atomicAdd(&hist[dst[e] >> 9], 1);
    }
    __syncthreads();
    if (t < NBUCK) bbc[t * NCHUNK + blockIdx.x] = hist[t];
}

__global__ void b_scan(int* __restrict__ bbc, int* __restrict__ bucketOff,
                       int* __restrict__ rowStart) {
    __shared__ int tot[NBUCK];
    int t = threadIdx.x;
    if (t < NBUCK) {
        int run = 0;
        for (int blk = 0; blk < NCHUNK; ++blk) {
            int idx = t * NCHUNK + blk;
            int c = bbc[idx];
            bbc[idx] = run;
            run += c;
        }
        tot[t] = run;
    }
    __syncthreads();
    if (t == 0) {
        int acc = 0;
        for (int b = 0; b < NBUCK; ++b) {
            bucketOff[b] = acc;
            acc += tot[b];
        }
        bucketOff[NBUCK] = acc;
        rowStart[N_NODES] = acc;
    }
}

__global__ __launch_bounds__(256) void b2_scatter(const int* __restrict__ src,
                                                  const int* __restrict__ dst,
                                                  const int* __restrict__ bbc,
                                                  const int* __restrict__ bucketOff,
                                                  int* __restrict__ staged) {
    __shared__ int cnt[NBUCK];
    __shared__ int base[NBUCK];
    int t = threadIdx.x;
    if (t < NBUCK) {
        cnt[t] = 0;
        base[t] = bucketOff[t] + bbc[t * NCHUNK + blockIdx.x];
    }
    __syncthreads();
    int ebase = blockIdx.x * EPB;
#pragma unroll
    for (int i = 0; i < EPB / 256; ++i) {
        int e = ebase + i * 256 + t;
        if (e < N_EDGES) {
            int d = dst[e];
            int b = d >> 9;
            int r = atomicAdd(&cnt[b], 1);
            staged[base[b] + r] = ((d & 511) << 17) | src[e];
        }
    }
}

__global__ __launch_bounds__(256) void b3_sort(const int* __restrict__ staged,
                                               const int* __restrict__ bucketOff,
                                               int* __restrict__ rowStart,
                                               float* __restrict__ normv,
                                               int* __restrict__ colIdx) {
    __shared__ int hist[NPB];
    __shared__ int sc0[NPB], sc1[NPB];
    __shared__ int cursor[NPB];
    int t = threadIdx.x;
    int b = blockIdx.x;
    int e0 = bucketOff[b], e1 = bucketOff[b + 1];
    int ne = e1 - e0;
    int node0 = b * NPB;
    int nn = min(NPB, N_NODES - node0);

    for (int j = t; j < NPB; j += 256) hist[j] = 0;
    __syncthreads();
    for (int idx = t; idx < ne; idx += 256)
        atomicAdd(&hist[staged[e0 + idx] >> 17], 1);
    __syncthreads();
    for (int j = t; j < NPB; j += 256) sc0[j] = hist[j];
    __syncthreads();
    int* s = sc0;
    int* d = sc1;
    for (int off = 1; off < NPB; off <<= 1) {
        for (int j = t; j < NPB; j += 256) d[j] = s[j] + (j >= off ? s[j - off] : 0);
        __syncthreads();
        int* tmp = s; s = d; d = tmp;
    }
    for (int j = t; j < NPB; j += 256) {
        int excl = s[j] - hist[j];
        cursor[j] = excl;
        if (j < nn) {
            rowStart[node0 + j] = e0 + excl;
            normv[node0 + j] = (float)(1.0 / sqrt((double)(hist[j] + 1)));
        }
    }
    __syncthreads();
    for (int idx = t; idx < ne; idx += 256) {
        int v = staged[e0 + idx];
        int dl = v >> 17;
        int sn = v & 0x1FFFF;
        int r = atomicAdd(&cursor[dl], 1);
        colIdx[e0 + r] = sn;
    }
}

// ================================================== weight prep (tiny)
__global__ void wc_kernel(const float* __restrict__ Wp, const float* __restrict__ bp,
                          const float* __restrict__ W1, float* __restrict__ Wc,
                          float* __restrict__ bc) {
    int r = blockIdx.x;
    int cc = threadIdx.x;
    float acc = 0.f;
    if (r < 256) {
        for (int k = 0; k < 128; ++k) acc = fmaf(Wp[r * 128 + k], W1[k * 128 + cc], acc);
        Wc[r * 128 + cc] = acc;
    } else {
        for (int k = 0; k < 128; ++k) acc = fmaf(bp[k], W1[k * 128 + cc], acc);
        bc[cc] = acc;
    }
}

// transpose + f16 hi/lo split: W[K][128] -> Oh/Ol[128][K]
__global__ void tsplit_kernel(const float* __restrict__ W, _Float16* __restrict__ Oh,
                              _Float16* __restrict__ Ol, int K) {
    int id = blockIdx.x * 256 + threadIdx.x;
    if (id >= K * 128) return;
    int n = id / K;
    int k = id - n * K;
    float v = W[k * 128 + n];
    _Float16 h = (_Float16)v;
    Oh[id] = h;
    Ol[id] = (_Float16)(v - (float)h);
}

// ================================ persistent-B barrier-free split-f16 GEMM
// C[r][c] = (sum_k A[r][k]*B[k][c] + bias[c]) * scale[r], stored fp16.
// Whole B (hi+lo) staged in LDS ONCE, XOR-swizzled on 16B granules: granule j
// of row n lives at group (j>>3), slot (j&7)^(n&7). After the single init
// barrier there are NO wave barriers: each of the 8 waves independently
// grid-strides over 16-row strips of A with depth-2 register prefetch of
// 32-k slabs.
// Round 2-4 post-mortem: every 512-thr variant compiled to a hard 128-VGPR
// cap, and WRITE/FETCH inflation scaled with strip count (36 KB/strip) ->
// the pre-RA scheduler was hoisting ALL unrolled slab loads to the strip
// top (64 extra live regs) and spilling. Fix: sched_barrier(0x38F) at each
// slab boundary pins VMEM motion (prefetch depth stays 2 = 16 regs) while
// letting ALU/SALU/VALU/MFMA/DS cross freely. Body ~90 regs < 128 cap.
template <bool AF16, int K>
__global__ __attribute__((amdgpu_waves_per_eu(1, 2)))
__launch_bounds__(512) void mfma_gemm_p(
    const float* __restrict__ Af, const _Float16* __restrict__ Ah,
    const _Float16* __restrict__ Bth, const _Float16* __restrict__ Btl,
    const float* __restrict__ bias, const float* __restrict__ scale,
    _Float16* __restrict__ Ch, int M, int nstrip) {
    constexpr int NSLAB = K / 32;
    constexpr int JROW = K / 8;          // 16B granules per B row
    __shared__ _Float16 sBh[128 * K];
    __shared__ _Float16 sBl[128 * K];

    const int t = threadIdx.x;
    // ---- stage all of B hi+lo, swizzled (write side of the involution)
    for (int idx = t; idx < 128 * JROW; idx += 512) {
        int n = idx / JROW;
        int j = idx - n * JROW;
        int d = n * K + (((j & 7) ^ (n & 7)) << 3) + ((j >> 3) << 6);
        *(half8*)&sBh[d] = *(const half8*)(Bth + n * K + (j << 3));
        *(half8*)&sBl[d] = *(const half8*)(Btl + n * K + (j << 3));
    }
    __syncthreads();

    const int lane = t & 63;
    const int q = lane >> 4;             // k-quad: k = q*8+jj within slab
    const int mr = lane & 15;            // row/col within 16x16 tile
    const int mre = mr & 7;
    const int gw = (blockIdx.x << 3) + (t >> 6);
    const int wstride = gridDim.x << 3;

    for (int strip = gw; strip < nstrip; strip += wstride) {
        const int row0 = strip * 16;
        int ar = row0 + mr;
        if (ar >= M) ar = M - 1;

        f32x4 acc[8];
#pragma unroll
        for (int nt = 0; nt < 8; ++nt) acc[nt] = (f32x4){0.f, 0.f, 0.f, 0.f};

        f32x4 pf[2][2];                  // fp32 A prefetch, 2 slabs deep
        half8 ph[2];                     // fp16 A prefetch, 2 slabs deep

#define LOAD_SLAB(SLOT, SS)                                                    \
        {                                                                      \
            if constexpr (AF16) {                                              \
                ph[SLOT] = *(const half8*)(Ah + (size_t)ar * K + (SS) * 32 + q * 8); \
            } else {                                                           \
                const float* ap = Af + (size_t)ar * K + (SS) * 32 + q * 8;     \
                pf[SLOT][0] = *(const f32x4*)ap;                               \
                pf[SLOT][1] = *(const f32x4*)(ap + 4);                         \
            }                                                                  \
        }

        LOAD_SLAB(0, 0)
        LOAD_SLAB(1, 1)

#pragma unroll
        for (int s = 0; s < NSLAB; ++s) {
            const int sl = s & 1;
            // ---- settle/convert current A fragment (loads issued 2 slabs ago)
            half8 ah, al;
            if constexpr (AF16) {
                ah = ph[sl];
            } else {
                f32x4 a0 = pf[sl][0];
                f32x4 a1 = pf[sl][1];
#pragma unroll
                for (int jj = 0; jj < 4; ++jj) {
                    _Float16 h0 = (_Float16)a0[jj];
                    _Float16 h1 = (_Float16)a1[jj];
                    ah[jj] = h0;
                    ah[jj + 4] = h1;
                    al[jj] = (_Float16)(a0[jj] - (float)h0);
                    al[jj + 4] = (_Float16)(a1[jj] - (float)h1);
                }
            }
            // ---- issue slab s+2 loads; they fly under this slab's MFMA burst
            if (s + 2 < NSLAB) LOAD_SLAB(sl, s + 2)

            // ---- MFMA burst; B from LDS (no barrier: B is static)
            // wanted granule j = s*4 + q  ->  group s>>1, slot ((s&1)*4|q)^mre
            const int kof = ((s >> 1) << 6) + ((((s & 1) << 2) | q) ^ mre) * 8;
#pragma unroll
            for (int nt = 0; nt < 8; ++nt) {
                const int bo = (nt * 16 + mr) * K + kof;
                half8 bh = *(const half8*)&sBh[bo];
                half8 bl = *(const half8*)&sBl[bo];
                acc[nt] = __builtin_amdgcn_mfma_f32_16x16x32_f16(ah, bh, acc[nt], 0, 0, 0);
                acc[nt] = __builtin_amdgcn_mfma_f32_16x16x32_f16(ah, bl, acc[nt], 0, 0, 0);
                if constexpr (!AF16)
                    acc[nt] = __builtin_amdgcn_mfma_f32_16x16x32_f16(al, bh, acc[nt], 0, 0, 0);
            }
            // ---- slab fence: VMEM may NOT cross (prefetch depth stays 2);
            // ALU|VALU|SALU|MFMA|DS (0x38F) schedule freely across slabs.
            __builtin_amdgcn_sched_barrier(0x38F);
        }
#undef LOAD_SLAB

        // ---- epilogue: C/D layout col=mr, row=q*4+rr (bias loaded here)
#pragma unroll
        for (int rr = 0; rr < 4; ++rr) {
            int row = row0 + q * 4 + rr;
            if (row >= M) continue;
            float sc = scale[row];
#pragma unroll
            for (int nt = 0; nt < 8; ++nt) {
                float bv = bias ? bias[nt * 16 + mr] : 0.f;
                Ch[(size_t)row * 128 + nt * 16 + mr] =
                    (_Float16)((acc[nt][rr] + bv) * sc);
            }
        }
    }
}

// ------------------------------------------------------------- aggregation
// zs fp16 pre-scaled by norm[row]. out = maybe_relu(norm[i]*(sum zs[src]+zs[i])+b)
__global__ __launch_bounds__(256) void agg_kernel(const _Float16* __restrict__ zs,
                                                  const int* __restrict__ rowStart,
                                                  const int* __restrict__ colIdx,
                                                  const float* __restrict__ normv,
                                                  const float* __restrict__ bias,
                                                  float* __restrict__ outF,
                                                  _Float16* __restrict__ outH,
                                                  int doRelu) {
    int wid = (blockIdx.x * 256 + threadIdx.x) >> 6;
    int lane = threadIdx.x & 63;
    if (wid >= N_NODES) return;
    int s0 = rowStart[wid];
    int s1 = rowStart[wid + 1];
    const int c = lane * 2;
    const _Float16* zc = zs + c;

    float2 a0 = make_float2(0.f, 0.f), a1 = a0, a2 = a0, a3 = a0;
    int e = s0;
    for (; e + 8 <= s1; e += 8) {
        int i0 = colIdx[e + 0], i1 = colIdx[e + 1], i2 = colIdx[e + 2], i3 = colIdx[e + 3];
        int i4 = colIdx[e + 4], i5 = colIdx[e + 5], i6 = colIdx[e + 6], i7 = colIdx[e + 7];
        half2v v0 = *(const half2v*)(zc + (size_t)i0 * 128);
        half2v v1 = *(const half2v*)(zc + (size_t)i1 * 128);
        half2v v2 = *(const half2v*)(zc + (size_t)i2 * 128);
        half2v v3 = *(const half2v*)(zc + (size_t)i3 * 128);
        half2v v4 = *(const half2v*)(zc + (size_t)i4 * 128);
        half2v v5 = *(const half2v*)(zc + (size_t)i5 * 128);
        half2v v6 = *(const half2v*)(zc + (size_t)i6 * 128);
        half2v v7 = *(const half2v*)(zc + (size_t)i7 * 128);
        a0.x += (float)v0[0] + (float)v4[0]; a0.y += (float)v0[1] + (float)v4[1];
        a1.x += (float)v1[0] + (float)v5[0]; a1.y += (float)v1[1] + (float)v5[1];
        a2.x += (float)v2[0] + (float)v6[0]; a2.y += (float)v2[1] + (float)v6[1];
        a3.x += (float)v3[0] + (float)v7[0]; a3.y += (float)v3[1] + (float)v7[1];
    }
    if (e + 4 <= s1) {
        int i0 = colIdx[e + 0], i1 = colIdx[e + 1], i2 = colIdx[e + 2], i3 = colIdx[e + 3];
        half2v v0 = *(const half2v*)(zc + (size_t)i0 * 128);
        half2v v1 = *(const half2v*)(zc + (size_t)i1 * 128);
        half2v v2 = *(const half2v*)(zc + (size_t)i2 * 128);
        half2v v3 = *(const half2v*)(zc + (size_t)i3 * 128);
        a0.x += (float)v0[0]; a0.y += (float)v0[1];
        a1.x += (float)v1[0]; a1.y += (float)v1[1];
        a2.x += (float)v2[0]; a2.y += (float)v2[1];
        a3.x += (float)v3[0]; a3.y += (float)v3[1];
        e += 4;
    }
    for (; e < s1; ++e) {
        int i0 = colIdx[e];
        half2v v0 = *(const half2v*)(zc + (size_t)i0 * 128);
        a0.x += (float)v0[0]; a0.y += (float)v0[1];
    }

    half2v self = *(const half2v*)(zc + (size_t)wid * 128);
    float sx = (a0.x + a1.x) + (a2.x + a3.x) + (float)self[0];
    float sy = (a0.y + a1.y) + (a2.y + a3.y) + (float)self[1];
    float nd = normv[wid];
    float2 bv = *(const float2*)(bias + c);
    float ox = fmaf(nd, sx, bv.x);
    float oy = fmaf(nd, sy, bv.y);
    if (doRelu) {
        ox = fmaxf(ox, 0.f);
        oy = fmaxf(oy, 0.f);
    }
    if (outH) {
        half2v o;
        o[0] = (_Float16)ox;
        o[1] = (_Float16)oy;
        *(half2v*)(outH + (size_t)wid * 128 + c) = o;
    } else {
        *(float2*)(outF + (size_t)wid * 128 + c) = make_float2(ox, oy);
    }
}

// ---------------------------------------------------------------- launcher
extern "C" void kernel_launch(void* const* d_in, const int* in_sizes, int n_in,
                              void* d_out, int out_size, void* d_ws, size_t ws_size,
                              hipStream_t stream) {
    const float* x  = (const float*)d_in[0];
    const int* ei   = (const int*)d_in[1];
    const float* Wp = (const float*)d_in[2];
    const float* bp = (const float*)d_in[3];
    const float* W1 = (const float*)d_in[4];
    const float* b1 = (const float*)d_in[5];
    const float* W2 = (const float*)d_in[6];
    const float* b2 = (const float*)d_in[7];
    float* out = (float*)d_out;

    const int* srcIdx = ei;
    const int* dstIdx = ei + N_EDGES;

    size_t off = 0;
    auto alloc = [&](size_t bytes) -> void* {
        void* p = (char*)d_ws + off;
        off += (bytes + 511) & ~(size_t)511;
        return p;
    };
    int* rowStart   = (int*)alloc((size_t)(N_NODES + 1) * 4);
    int* colIdx     = (int*)alloc((size_t)N_EDGES * 4);
    int* staged     = (int*)alloc((size_t)N_EDGES * 4);
    int* bbc        = (int*)alloc((size_t)NBUCK * NCHUNK * 4);
    int* bucketOff  = (int*)alloc((size_t)(NBUCK + 1) * 4);
    float* normv    = (float*)alloc((size_t)N_NODES * 4);
    float* Wc       = (float*)alloc((size_t)256 * 128 * 4);
    float* bc       = (float*)alloc((size_t)128 * 4);
    _Float16* Wcth  = (_Float16*)alloc((size_t)128 * 256 * 2);
    _Float16* Wctl  = (_Float16*)alloc((size_t)128 * 256 * 2);
    _Float16* W2th  = (_Float16*)alloc((size_t)128 * 128 * 2);
    _Float16* W2tl  = (_Float16*)alloc((size_t)128 * 128 * 2);
    _Float16* zA    = (_Float16*)alloc((size_t)N_NODES * 128 * 2);
    _Float16* zB    = (_Float16*)alloc((size_t)N_NODES * 128 * 2);

    const int AB = (N_NODES + 3) / 4;           // 25000 (agg: 1 wave/node)
    constexpr int NSTRIP = (N_NODES + 15) / 16; // 6250 strips of 16 rows

    // ---- CSR build (bucketed counting sort) ----
    b1_hist<<<NCHUNK, 256, 0, stream>>>(dstIdx, bbc);
    b_scan<<<1, 256, 0, stream>>>(bbc, bucketOff, rowStart);
    b2_scatter<<<NCHUNK, 256, 0, stream>>>(srcIdx, dstIdx, bbc, bucketOff, staged);
    b3_sort<<<NBUCK, 256, 0, stream>>>(staged, bucketOff, rowStart, normv, colIdx);

    // ---- weight prep ----
    wc_kernel<<<257, 128, 0, stream>>>(Wp, bp, W1, Wc, bc);
    tsplit_kernel<<<(256 * 128 + 255) / 256, 256, 0, stream>>>(Wc, Wcth, Wctl, 256);
    tsplit_kernel<<<(128 * 128 + 255) / 256, 256, 0, stream>>>(W2, W2th, W2tl, 128);

    // ---- pipeline (all intermediates fp16, pre-scaled by norm) ----
    // zA = f16[(x @ Wc + bc) * norm]   (persistent-B, barrier-free)
    mfma_gemm_p<false, 256><<<256, 512, 0, stream>>>(x, nullptr, Wcth, Wctl, bc, normv,
                                                     zA, N_NODES, NSTRIP);
    // zB = f16[relu(norm*(sum zA[src] + zA[self]) + b1)]
    agg_kernel<<<AB, 256, 0, stream>>>(zA, rowStart, colIdx, normv, b1, nullptr, zB, 1);
    // zA (reused) = f16[(zB @ W2) * norm]   — A fp16, 2-product path
    mfma_gemm_p<true, 128><<<256, 512, 0, stream>>>(nullptr, zB, W2th, W2tl, nullptr, normv,
                                                    zA, N_NODES, NSTRIP);
    // out = fp32[norm*(sum zA[src] + zA[self]) + b2]
    agg_kernel<<<AB, 256, 0, stream>>>(zA, rowStart, colIdx, normv, b2, out, nullptr, 0);
}

// Round 7
// 437.688 us; speedup vs baseline: 1.4984x; 1.0516x over previous
//
#include <hip/hip_runtime.h>
#include <cstdint>
#include <cstddef>

#define N_NODES 100000
#define N_EDGES 1600000

// ---- bucketed counting-sort CSR parameters ----
constexpr int NPB = 512;                               // nodes per bucket (2^9)
constexpr int NBUCK = (N_NODES + NPB - 1) / NPB;       // 196
constexpr int EPB = 8192;                              // edges per block in B1/B2
constexpr int NCHUNK = (N_EDGES + EPB - 1) / EPB;      // 196

typedef _Float16 half8 __attribute__((ext_vector_type(8)));
typedef _Float16 half2v __attribute__((ext_vector_type(2)));
typedef float f32x4 __attribute__((ext_vector_type(4)));

// ================================================================= CSR build
__global__ __launch_bounds__(256) void b1_hist(const int* __restrict__ dst,
                                               int* __restrict__ bbc) {
    __shared__ int hist[NBUCK];
    int t = threadIdx.x;
    if (t < NBUCK) hist[t] = 0;
    __syncthreads();
    int base = blockIdx.x * EPB;
#pragma unroll
    for (int i = 0; i < EPB / 256; ++i) {
        int e = base + i * 256 + t;
        if (e < N_EDGES) atomicAdd(&hist[dst[e] >> 9], 1);
    }
    __syncthreads();
    if (t < NBUCK) bbc[t * NCHUNK + blockIdx.x] = hist[t];
}

__global__ void b_scan(int* __restrict__ bbc, int* __restrict__ bucketOff,
                       int* __restrict__ rowStart) {
    __shared__ int tot[NBUCK];
    int t = threadIdx.x;
    if (t < NBUCK) {
        int run = 0;
        for (int blk = 0; blk < NCHUNK; ++blk) {
            int idx = t * NCHUNK + blk;
            int c = bbc[idx];
            bbc[idx] = run;
            run += c;
        }
        tot[t] = run;
    }
    __syncthreads();
    if (t == 0) {
        int acc = 0;
        for (int b = 0; b < NBUCK; ++b) {
            bucketOff[b] = acc;
            acc += tot[b];
        }
        bucketOff[NBUCK] = acc;
        rowStart[N_NODES] = acc;
    }
}

__global__ __launch_bounds__(256) void b2_scatter(const int* __restrict__ src,
                                                  const int* __restrict__ dst,
                                                  const int* __restrict__ bbc,
                                                  const int* __restrict__ bucketOff,
                                                  int* __restrict__ staged) {
    __shared__ int cnt[NBUCK];
    __shared__ int base[NBUCK];
    int t = threadIdx.x;
    if (t < NBUCK) {
        cnt[t] = 0;
        base[t] = bucketOff[t] + bbc[t * NCHUNK + blockIdx.x];
    }
    __syncthreads();
    int ebase = blockIdx.x * EPB;
#pragma unroll
    for (int i = 0; i < EPB / 256; ++i) {
        int e = ebase + i * 256 + t;
        if (e < N_EDGES) {
            int d = dst[e];
            int b = d >> 9;
            int r = atomicAdd(&cnt[b], 1);
            staged[base[b] + r] = ((d & 511) << 17) | src[e];
        }
    }
}

__global__ __launch_bounds__(256) void b3_sort(const int* __restrict__ staged,
                                               const int* __restrict__ bucketOff,
                                               int* __restrict__ rowStart,
                                               float* __restrict__ normv,
                                               int* __restrict__ colIdx) {
    __shared__ int hist[NPB];
    __shared__ int sc0[NPB], sc1[NPB];
    __shared__ int cursor[NPB];
    int t = threadIdx.x;
    int b = blockIdx.x;
    int e0 = bucketOff[b], e1 = bucketOff[b + 1];
    int ne = e1 - e0;
    int node0 = b * NPB;
    int nn = min(NPB, N_NODES - node0);

    for (int j = t; j < NPB; j += 256) hist[j] = 0;
    __syncthreads();
    for (int idx = t; idx < ne; idx += 256)
        atomicAdd(&hist[staged[e0 + idx] >> 17], 1);
    __syncthreads();
    for (int j = t; j < NPB; j += 256) sc0[j] = hist[j];
    __syncthreads();
    int* s = sc0;
    int* d = sc1;
    for (int off = 1; off < NPB; off <<= 1) {
        for (int j = t; j < NPB; j += 256) d[j] = s[j] + (j >= off ? s[j - off] : 0);
        __syncthreads();
        int* tmp = s; s = d; d = tmp;
    }
    for (int j = t; j < NPB; j += 256) {
        int excl = s[j] - hist[j];
        cursor[j] = excl;
        if (j < nn) {
            rowStart[node0 + j] = e0 + excl;
            normv[node0 + j] = (float)(1.0 / sqrt((double)(hist[j] + 1)));
        }
    }
    __syncthreads();
    for (int idx = t; idx < ne; idx += 256) {
        int v = staged[e0 + idx];
        int dl = v >> 17;
        int sn = v & 0x1FFFF;
        int r = atomicAdd(&cursor[dl], 1);
        colIdx[e0 + r] = sn;
    }
}

// ================================================== weight prep (tiny)
__global__ void wc_kernel(const float* __restrict__ Wp, const float* __restrict__ bp,
                          const float* __restrict__ W1, float* __restrict__ Wc,
                          float* __restrict__ bc) {
    int r = blockIdx.x;
    int cc = threadIdx.x;
    float acc = 0.f;
    if (r < 256) {
        for (int k = 0; k < 128; ++k) acc = fmaf(Wp[r * 128 + k], W1[k * 128 + cc], acc);
        Wc[r * 128 + cc] = acc;
    } else {
        for (int k = 0; k < 128; ++k) acc = fmaf(bp[k], W1[k * 128 + cc], acc);
        bc[cc] = acc;
    }
}

// transpose + f16 hi/lo split: W[K][128] -> Oh/Ol[128][K]
__global__ void tsplit_kernel(const float* __restrict__ W, _Float16* __restrict__ Oh,
                              _Float16* __restrict__ Ol, int K) {
    int id = blockIdx.x * 256 + threadIdx.x;
    if (id >= K * 128) return;
    int n = id / K;
    int k = id - n * K;
    float v = W[k * 128 + n];
    _Float16 h = (_Float16)v;
    Oh[id] = h;
    Ol[id] = (_Float16)(v - (float)h);
}

// ================================ persistent-B barrier-free split-f16 GEMM
// C[r][c] = (sum_k A[r][k]*B[k][c] + bias[c]) * scale[r], stored fp16.
// Whole B (hi+lo) staged in LDS ONCE, XOR-swizzled on 16B granules: granule j
// of row n lives at group (j>>3), slot (j&7)^(n&7). After the single init
// barrier there are NO wave barriers: each of the 16 waves independently
// grid-strides over 16-row strips of A with depth-2 register prefetch of
// 32-k slabs.
// Round 2-4 post-mortem: the pre-RA scheduler hoisted ALL unrolled slab
// loads to the strip top (+64 live regs) and spilled ~36 KB/strip of
// scratch. sched_barrier(0x38F) at each slab boundary pins VMEM motion
// (prefetch depth stays 2) while ALU/SALU/VALU/MFMA/DS cross freely; with
// it the body allocates 108 VGPRs, zero scratch (round 5: WRITE_SIZE
// exactly = output bytes).
// Round 5 post-mortem: 512-thr block = 2 waves/SIMD was latency-starved
// (all pipes <16%). 1024-thr block = 4 waves/SIMD; launch_bounds(1024)
// caps VGPR at 128 >= 108, so the working body is unchanged.
template <bool AF16, int K>
__global__ __launch_bounds__(1024) void mfma_gemm_p(
    const float* __restrict__ Af, const _Float16* __restrict__ Ah,
    const _Float16* __restrict__ Bth, const _Float16* __restrict__ Btl,
    const float* __restrict__ bias, const float* __restrict__ scale,
    _Float16* __restrict__ Ch, int M, int nstrip) {
    constexpr int NSLAB = K / 32;
    constexpr int JROW = K / 8;          // 16B granules per B row
    __shared__ _Float16 sBh[128 * K];
    __shared__ _Float16 sBl[128 * K];

    const int t = threadIdx.x;
    // ---- stage all of B hi+lo, swizzled (write side of the involution)
    for (int idx = t; idx < 128 * JROW; idx += 1024) {
        int n = idx / JROW;
        int j = idx - n * JROW;
        int d = n * K + (((j & 7) ^ (n & 7)) << 3) + ((j >> 3) << 6);
        *(half8*)&sBh[d] = *(const half8*)(Bth + n * K + (j << 3));
        *(half8*)&sBl[d] = *(const half8*)(Btl + n * K + (j << 3));
    }
    __syncthreads();

    const int lane = t & 63;
    const int q = lane >> 4;             // k-quad: k = q*8+jj within slab
    const int mr = lane & 15;            // row/col within 16x16 tile
    const int mre = mr & 7;
    const int gw = (blockIdx.x << 4) + (t >> 6);
    const int wstride = gridDim.x << 4;

    for (int strip = gw; strip < nstrip; strip += wstride) {
        const int row0 = strip * 16;
        int ar = row0 + mr;
        if (ar >= M) ar = M - 1;

        f32x4 acc[8];
#pragma unroll
        for (int nt = 0; nt < 8; ++nt) acc[nt] = (f32x4){0.f, 0.f, 0.f, 0.f};

        f32x4 pf[2][2];                  // fp32 A prefetch, 2 slabs deep
        half8 ph[2];                     // fp16 A prefetch, 2 slabs deep

#define LOAD_SLAB(SLOT, SS)                                                    \
        {                                                                      \
            if constexpr (AF16) {                                              \
                ph[SLOT] = *(const half8*)(Ah + (size_t)ar * K + (SS) * 32 + q * 8); \
            } else {                                                           \
                const float* ap = Af + (size_t)ar * K + (SS) * 32 + q * 8;     \
                pf[SLOT][0] = *(const f32x4*)ap;                               \
                pf[SLOT][1] = *(const f32x4*)(ap + 4);                         \
            }                                                                  \
        }

        LOAD_SLAB(0, 0)
        LOAD_SLAB(1, 1)

#pragma unroll
        for (int s = 0; s < NSLAB; ++s) {
            const int sl = s & 1;
            // ---- settle/convert current A fragment (loads issued 2 slabs ago)
            half8 ah, al;
            if constexpr (AF16) {
                ah = ph[sl];
            } else {
                f32x4 a0 = pf[sl][0];
                f32x4 a1 = pf[sl][1];
#pragma unroll
                for (int jj = 0; jj < 4; ++jj) {
                    _Float16 h0 = (_Float16)a0[jj];
                    _Float16 h1 = (_Float16)a1[jj];
                    ah[jj] = h0;
                    ah[jj + 4] = h1;
                    al[jj] = (_Float16)(a0[jj] - (float)h0);
                    al[jj + 4] = (_Float16)(a1[jj] - (float)h1);
                }
            }
            // ---- issue slab s+2 loads; they fly under this slab's MFMA burst
            if (s + 2 < NSLAB) LOAD_SLAB(sl, s + 2)

            // ---- MFMA burst; B from LDS (no barrier: B is static)
            // wanted granule j = s*4 + q  ->  group s>>1, slot ((s&1)*4|q)^mre
            const int kof = ((s >> 1) << 6) + ((((s & 1) << 2) | q) ^ mre) * 8;
#pragma unroll
            for (int nt = 0; nt < 8; ++nt) {
                const int bo = (nt * 16 + mr) * K + kof;
                half8 bh = *(const half8*)&sBh[bo];
                half8 bl = *(const half8*)&sBl[bo];
                acc[nt] = __builtin_amdgcn_mfma_f32_16x16x32_f16(ah, bh, acc[nt], 0, 0, 0);
                acc[nt] = __builtin_amdgcn_mfma_f32_16x16x32_f16(ah, bl, acc[nt], 0, 0, 0);
                if constexpr (!AF16)
                    acc[nt] = __builtin_amdgcn_mfma_f32_16x16x32_f16(al, bh, acc[nt], 0, 0, 0);
            }
            // ---- slab fence: VMEM may NOT cross (prefetch depth stays 2);
            // ALU|VALU|SALU|MFMA|DS (0x38F) schedule freely across slabs.
            __builtin_amdgcn_sched_barrier(0x38F);
        }
#undef LOAD_SLAB

        // ---- epilogue: C/D layout col=mr, row=q*4+rr (bias loaded here)
#pragma unroll
        for (int rr = 0; rr < 4; ++rr) {
            int row = row0 + q * 4 + rr;
            if (row >= M) continue;
            float sc = scale[row];
#pragma unroll
            for (int nt = 0; nt < 8; ++nt) {
                float bv = bias ? bias[nt * 16 + mr] : 0.f;
                Ch[(size_t)row * 128 + nt * 16 + mr] =
                    (_Float16)((acc[nt][rr] + bv) * sc);
            }
        }
    }
}

// ------------------------------------------------------------- aggregation
// zs fp16 pre-scaled by norm[row]. out = maybe_relu(norm[i]*(sum zs[src]+zs[i])+b)
__global__ __launch_bounds__(256) void agg_kernel(const _Float16* __restrict__ zs,
                                                  const int* __restrict__ rowStart,
                                                  const int* __restrict__ colIdx,
                                                  const float* __restrict__ normv,
                                                  const float* __restrict__ bias,
                                                  float* __restrict__ outF,
                                                  _Float16* __restrict__ outH,
                                                  int doRelu) {
    int wid = (blockIdx.x * 256 + threadIdx.x) >> 6;
    int lane = threadIdx.x & 63;
    if (wid >= N_NODES) return;
    int s0 = rowStart[wid];
    int s1 = rowStart[wid + 1];
    const int c = lane * 2;
    const _Float16* zc = zs + c;

    float2 a0 = make_float2(0.f, 0.f), a1 = a0, a2 = a0, a3 = a0;
    int e = s0;
    for (; e + 8 <= s1; e += 8) {
        int i0 = colIdx[e + 0], i1 = colIdx[e + 1], i2 = colIdx[e + 2], i3 = colIdx[e + 3];
        int i4 = colIdx[e + 4], i5 = colIdx[e + 5], i6 = colIdx[e + 6], i7 = colIdx[e + 7];
        half2v v0 = *(const half2v*)(zc + (size_t)i0 * 128);
        half2v v1 = *(const half2v*)(zc + (size_t)i1 * 128);
        half2v v2 = *(const half2v*)(zc + (size_t)i2 * 128);
        half2v v3 = *(const half2v*)(zc + (size_t)i3 * 128);
        half2v v4 = *(const half2v*)(zc + (size_t)i4 * 128);
        half2v v5 = *(const half2v*)(zc + (size_t)i5 * 128);
        half2v v6 = *(const half2v*)(zc + (size_t)i6 * 128);
        half2v v7 = *(const half2v*)(zc + (size_t)i7 * 128);
        a0.x += (float)v0[0] + (float)v4[0]; a0.y += (float)v0[1] + (float)v4[1];
        a1.x += (float)v1[0] + (float)v5[0]; a1.y += (float)v1[1] + (float)v5[1];
        a2.x += (float)v2[0] + (float)v6[0]; a2.y += (float)v2[1] + (float)v6[1];
        a3.x += (float)v3[0] + (float)v7[0]; a3.y += (float)v3[1] + (float)v7[1];
    }
    if (e + 4 <= s1) {
        int i0 = colIdx[e + 0], i1 = colIdx[e + 1], i2 = colIdx[e + 2], i3 = colIdx[e + 3];
        half2v v0 = *(const half2v*)(zc + (size_t)i0 * 128);
        half2v v1 = *(const half2v*)(zc + (size_t)i1 * 128);
        half2v v2 = *(const half2v*)(zc + (size_t)i2 * 128);
        half2v v3 = *(const half2v*)(zc + (size_t)i3 * 128);
        a0.x += (float)v0[0]; a0.y += (float)v0[1];
        a1.x += (float)v1[0]; a1.y += (float)v1[1];
        a2.x += (float)v2[0]; a2.y += (float)v2[1];
        a3.x += (float)v3[0]; a3.y += (float)v3[1];
        e += 4;
    }
    for (; e < s1; ++e) {
        int i0 = colIdx[e];
        half2v v0 = *(const half2v*)(zc + (size_t)i0 * 128);
        a0.x += (float)v0[0]; a0.y += (float)v0[1];
    }

    half2v self = *(const half2v*)(zc + (size_t)wid * 128);
    float sx = (a0.x + a1.x) + (a2.x + a3.x) + (float)self[0];
    float sy = (a0.y + a1.y) + (a2.y + a3.y) + (float)self[1];
    float nd = normv[wid];
    float2 bv = *(const float2*)(bias + c);
    float ox = fmaf(nd, sx, bv.x);
    float oy = fmaf(nd, sy, bv.y);
    if (doRelu) {
        ox = fmaxf(ox, 0.f);
        oy = fmaxf(oy, 0.f);
    }
    if (outH) {
        half2v o;
        o[0] = (_Float16)ox;
        o[1] = (_Float16)oy;
        *(half2v*)(outH + (size_t)wid * 128 + c) = o;
    } else {
        *(float2*)(outF + (size_t)wid * 128 + c) = make_float2(ox, oy);
    }
}

// ---------------------------------------------------------------- launcher
extern "C" void kernel_launch(void* const* d_in, const int* in_sizes, int n_in,
                              void* d_out, int out_size, void* d_ws, size_t ws_size,
                              hipStream_t stream) {
    const float* x  = (const float*)d_in[0];
    const int* ei   = (const int*)d_in[1];
    const float* Wp = (const float*)d_in[2];
    const float* bp = (const float*)d_in[3];
    const float* W1 = (const float*)d_in[4];
    const float* b1 = (const float*)d_in[5];
    const float* W2 = (const float*)d_in[6];
    const float* b2 = (const float*)d_in[7];
    float* out = (float*)d_out;

    const int* srcIdx = ei;
    const int* dstIdx = ei + N_EDGES;

    size_t off = 0;
    auto alloc = [&](size_t bytes) -> void* {
        void* p = (char*)d_ws + off;
        off += (bytes + 511) & ~(size_t)511;
        return p;
    };
    int* rowStart   = (int*)alloc((size_t)(N_NODES + 1) * 4);
    int* colIdx     = (int*)alloc((size_t)N_EDGES * 4);
    int* staged     = (int*)alloc((size_t)N_EDGES * 4);
    int* bbc        = (int*)alloc((size_t)NBUCK * NCHUNK * 4);
    int* bucketOff  = (int*)alloc((size_t)(NBUCK + 1) * 4);
    float* normv    = (float*)alloc((size_t)N_NODES * 4);
    float* Wc       = (float*)alloc((size_t)256 * 128 * 4);
    float* bc       = (float*)alloc((size_t)128 * 4);
    _Float16* Wcth  = (_Float16*)alloc((size_t)128 * 256 * 2);
    _Float16* Wctl  = (_Float16*)alloc((size_t)128 * 256 * 2);
    _Float16* W2th  = (_Float16*)alloc((size_t)128 * 128 * 2);
    _Float16* W2tl  = (_Float16*)alloc((size_t)128 * 128 * 2);
    _Float16* zA    = (_Float16*)alloc((size_t)N_NODES * 128 * 2);
    _Float16* zB    = (_Float16*)alloc((size_t)N_NODES * 128 * 2);

    const int AB = (N_NODES + 3) / 4;           // 25000 (agg: 1 wave/node)
    constexpr int NSTRIP = (N_NODES + 15) / 16; // 6250 strips of 16 rows

    // ---- CSR build (bucketed counting sort) ----
    b1_hist<<<NCHUNK, 256, 0, stream>>>(dstIdx, bbc);
    b_scan<<<1, 256, 0, stream>>>(bbc, bucketOff, rowStart);
    b2_scatter<<<NCHUNK, 256, 0, stream>>>(srcIdx, dstIdx, bbc, bucketOff, staged);
    b3_sort<<<NBUCK, 256, 0, stream>>>(staged, bucketOff, rowStart, normv, colIdx);

    // ---- weight prep ----
    wc_kernel<<<257, 128, 0, stream>>>(Wp, bp, W1, Wc, bc);
    tsplit_kernel<<<(256 * 128 + 255) / 256, 256, 0, stream>>>(Wc, Wcth, Wctl, 256);
    tsplit_kernel<<<(128 * 128 + 255) / 256, 256, 0, stream>>>(W2, W2th, W2tl, 128);

    // ---- pipeline (all intermediates fp16, pre-scaled by norm) ----
    // zA = f16[(x @ Wc + bc) * norm]   (persistent-B, 16 waves/block)
    mfma_gemm_p<false, 256><<<256, 1024, 0, stream>>>(x, nullptr, Wcth, Wctl, bc, normv,
                                                      zA, N_NODES, NSTRIP);
    // zB = f16[relu(norm*(sum zA[src] + zA[self]) + b1)]
    agg_kernel<<<AB, 256, 0, stream>>>(zA, rowStart, colIdx, normv, b1, nullptr, zB, 1);
    // zA (reused) = f16[(zB @ W2) * norm]   — A fp16, 2-product path
    mfma_gemm_p<true, 128><<<256, 1024, 0, stream>>>(nullptr, zB, W2th, W2tl, nullptr, normv,
                                                     zA, N_NODES, NSTRIP);
    // out = fp32[norm*(sum zA[src] + zA[self]) + b2]
    agg_kernel<<<AB, 256, 0, stream>>>(zA, rowStart, colIdx, normv, b2, out, nullptr, 0);
}